// Round 8
// baseline (1062.056 us; speedup 1.0000x reference)
//
#include <hip/hip_runtime.h>

// CNF forward: 8 fixed dopri5 steps x 6 stages, rows independent.
// R8 = R7 skeleton with per-stage work-sum cuts (R7 showed dur invariant to
// occupancy: wall = serialized VALU+LDS+MFMA per stage, so shrink the sum):
//  (1) bias K-augmentation: mm1 gets a 3rd K-chunk with features (t, 1) so
//      ua = W1a^T y + W1t*t + b1 comes out of MFMA; sBW LDS array deleted.
//  (2) mm2 K-partial: each wave computes all 64 douts over its OWN 64 j's
//      (8 MFMAs, W2^T own-j frags in regs), exchanges 16 bf16 partials via
//      padded LDS (4 b64 W + 4 b64 R) instead of full-h read (8 b128 -> 2).
//      h write->own-read is wave-local, ordered by __threadfence_block().
// Layout per 4-wave group (16 rows): wave Q owns j in [Q*64,+64), z cols
// [Q*16,+16). 1024 blocks x 512 threads (2 groups/block).

typedef __bf16 bf16x8 __attribute__((ext_vector_type(8)));
typedef __bf16 bf16x4 __attribute__((ext_vector_type(4)));
typedef float  f32x4  __attribute__((ext_vector_type(4)));
typedef unsigned int u32;
typedef u32 u32x2 __attribute__((ext_vector_type(2)));
typedef u32 u32x4 __attribute__((ext_vector_type(4)));

#define MFMA16(a, b, c) __builtin_amdgcn_mfma_f32_16x16x32_bf16((a), (b), (c), 0, 0, 0)

__device__ __forceinline__ u32 bfbits(float x) {
    __bf16 b = (__bf16)x;                      // RNE fp32->bf16
    return (u32)__builtin_bit_cast(unsigned short, b);
}
__device__ __forceinline__ float frombits(u32 u16) {
    return __builtin_bit_cast(float, u16 << 16);
}
__device__ __forceinline__ u32 pack2(float lo, float hi) {
    return bfbits(lo) | (bfbits(hi) << 16);
}
__device__ __forceinline__ float fast_tanh(float x) {
    float e = __expf(2.0f * x);
    return 1.0f - 2.0f * __builtin_amdgcn_rcpf(e + 1.0f);
}

extern "C" __global__ __attribute__((amdgpu_waves_per_eu(4))) void
__launch_bounds__(512)
cnf_kernel(const float* __restrict__ Yg, const float* __restrict__ Eg,
           const float* __restrict__ W1g, const float* __restrict__ b1g,
           const float* __restrict__ W2g, const float* __restrict__ b2g,
           float* __restrict__ Og)
{
    // ---- LDS ~40 KB ----
    __shared__ __align__(16) __bf16 sY[2][16 * 72];      // per-GROUP y [batch][d]
    __shared__ __align__(16) __bf16 sH[2][16 * 264];     // per-GROUP h [batch][j] (own-j use only)
    __shared__ __align__(16) __bf16 sFA[2][4][16 * 68];  // per-GROUP fa partials [w][batch][dout], pad 68
    __shared__ float sRedSS[128], sRedLP[128];

    const int tid  = threadIdx.x;
    const int wave = tid >> 6;
    const int lane = tid & 63;
    const int quad = lane >> 4;
    const int l16  = lane & 15;
    const int grp  = wave >> 2;
    const int Q    = wave & 3;
    const int colb = Q * 16;          // own z-col tile base
    const int jb   = Q * 64;          // own hidden-j base
    const int row  = blockIdx.x * 32 + grp * 16 + l16;

    // ---------------- W1 fragments (A-op: [m=j(l16)][k=d(quad*8+i)]) ----------------
    bf16x8 w1f[8];
#define LDW1(t, h) { \
    bf16x8 f; \
    _Pragma("unroll") \
    for (int i = 0; i < 8; ++i) \
        f[i] = (__bf16)W1g[((h)*32 + quad*8 + i) * 256 + jb + (t)*16 + l16]; \
    w1f[(t)*2 + (h)] = f; }
    LDW1(0,0) LDW1(0,1) LDW1(1,0) LDW1(1,1) LDW1(2,0) LDW1(2,1) LDW1(3,0) LDW1(3,1)

    // ---------------- W2^T frags for K-partial mm2: [m=dout(l16)][k=own-j(quad*8+i)] ----
    bf16x8 w2f[8];   // [td*2 + c]
#define LDW2(td, c) { \
    bf16x8 f; \
    _Pragma("unroll") \
    for (int i = 0; i < 8; ++i) \
        f[i] = (__bf16)W2g[(jb + (c)*32 + quad*8 + i) * 64 + (td)*16 + l16]; \
    w2f[(td)*2 + (c)] = f; }
    LDW2(0,0) LDW2(0,1) LDW2(1,0) LDW2(1,1) LDW2(2,0) LDW2(2,1) LDW2(3,0) LDW2(3,1)

    // ---------------- bias A-frag payload: k=0 -> W1_t[j], k=1 -> b1[j] ----------------
    u32 w1x[4];
    #pragma unroll
    for (int t = 0; t < 4; ++t) {
        int j = jb + t * 16 + l16;
        w1x[t] = (quad == 0) ? pack2(W1g[64 * 256 + j], b1g[j]) : 0u;
    }

    // ---------------- e fragments direct from global ----------------
    bf16x8 ae0, ae1;
    {
        f32x4 ea = *(const f32x4*)(Eg + row * 64 + quad * 8);
        f32x4 eb = *(const f32x4*)(Eg + row * 64 + quad * 8 + 4);
        f32x4 ec = *(const f32x4*)(Eg + row * 64 + 32 + quad * 8);
        f32x4 ed = *(const f32x4*)(Eg + row * 64 + 32 + quad * 8 + 4);
        ae0[0]=(__bf16)ea[0]; ae0[1]=(__bf16)ea[1]; ae0[2]=(__bf16)ea[2]; ae0[3]=(__bf16)ea[3];
        ae0[4]=(__bf16)eb[0]; ae0[5]=(__bf16)eb[1]; ae0[6]=(__bf16)eb[2]; ae0[7]=(__bf16)eb[3];
        ae1[0]=(__bf16)ec[0]; ae1[1]=(__bf16)ec[1]; ae1[2]=(__bf16)ec[2]; ae1[3]=(__bf16)ec[3];
        ae1[4]=(__bf16)ed[0]; ae1[5]=(__bf16)ed[1]; ae1[6]=(__bf16)ed[2]; ae1[7]=(__bf16)ed[3];
    }

    // ------------- precompute ghv = gh0 .* v, both [j=quad*4+r][batch=l16] (R7-proven) ----
    u32 ghvp[8];
#define PRE(t) { \
    f32x4 vacc = {0.f, 0.f, 0.f, 0.f}; \
    vacc = MFMA16(w1f[(t)*2 + 0], ae0, vacc); \
    vacc = MFMA16(w1f[(t)*2 + 1], ae1, vacc); \
    const float* wrow = W2g + (jb + (t)*16 + l16) * 64; \
    f32x4 wa = *(const f32x4*)(wrow + quad * 8); \
    f32x4 wb = *(const f32x4*)(wrow + quad * 8 + 4); \
    f32x4 wc = *(const f32x4*)(wrow + 32 + quad * 8); \
    f32x4 wd = *(const f32x4*)(wrow + 32 + quad * 8 + 4); \
    bf16x8 aw0, aw1; \
    aw0[0]=(__bf16)wa[0]; aw0[1]=(__bf16)wa[1]; aw0[2]=(__bf16)wa[2]; aw0[3]=(__bf16)wa[3]; \
    aw0[4]=(__bf16)wb[0]; aw0[5]=(__bf16)wb[1]; aw0[6]=(__bf16)wb[2]; aw0[7]=(__bf16)wb[3]; \
    aw1[0]=(__bf16)wc[0]; aw1[1]=(__bf16)wc[1]; aw1[2]=(__bf16)wc[2]; aw1[3]=(__bf16)wc[3]; \
    aw1[4]=(__bf16)wd[0]; aw1[5]=(__bf16)wd[1]; aw1[6]=(__bf16)wd[2]; aw1[7]=(__bf16)wd[3]; \
    f32x4 gacc = {0.f, 0.f, 0.f, 0.f}; \
    gacc = MFMA16(aw0, ae0, gacc); \
    gacc = MFMA16(aw1, ae1, gacc); \
    ghvp[(t)*2 + 0] = pack2(gacc[0] * vacc[0], gacc[1] * vacc[1]); \
    ghvp[(t)*2 + 1] = pack2(gacc[2] * vacc[2], gacc[3] * vacc[3]); }
    PRE(0) PRE(1) PRE(2) PRE(3)

    // ---------------- z state + b2 (batch=l16, d=colb+quad*4+r) ----------------
    f32x4 zv  = *(const f32x4*)(Yg + row * 64 + colb + quad * 4);
    f32x4 bb2 = *(const f32x4*)(b2g + colb + quad * 4);

    __bf16* yb = sY[grp];
    __bf16* hb = sH[grp];
    __bf16* fw = &sFA[grp][Q][0];

    const float dt = 0.125f;
    u32 kp[6][2];     // k_dz bf16x2: [stage][pair], d = colb + quad*4 + {0..3}
    float lp = 0.f;

#define KV(s, g) frombits(((g) & 1) ? (kp[s][(g)>>1] >> 16) : (kp[s][(g)>>1] & 0xffffu))

#define S1A(g) (0.2f*KV(0,g))
#define S2A(g) (0.075f*KV(0,g) + 0.225f*KV(1,g))
#define S3A(g) ((44.f/45.f)*KV(0,g) + (-56.f/15.f)*KV(1,g) + (32.f/9.f)*KV(2,g))
#define S4A(g) ((19372.f/6561.f)*KV(0,g) + (-25360.f/2187.f)*KV(1,g) + \
                (64448.f/6561.f)*KV(2,g) + (-212.f/729.f)*KV(3,g))
#define S5A(g) ((9017.f/3168.f)*KV(0,g) + (-355.f/33.f)*KV(1,g) + \
                (46732.f/5247.f)*KV(2,g) + (49.f/176.f)*KV(3,g) + (-5103.f/18656.f)*KV(4,g))
#define CBA(g) ((35.f/384.f)*KV(0,g) + (500.f/1113.f)*KV(2,g) + (125.f/192.f)*KV(3,g) + \
                (-2187.f/6784.f)*KV(4,g) + (11.f/84.f)*KV(5,g))

    // mm1 tile: 2 data K-chunks + bias K-chunk (t,1); h -> hb (own-j region)
#define MM1T(t) { \
    f32x4 ua = {0.f, 0.f, 0.f, 0.f}; \
    ua = MFMA16(w1f[(t)*2 + 0], a10, ua); \
    ua = MFMA16(w1f[(t)*2 + 1], a11, ua); \
    u32x4 az = {w1x[t], 0u, 0u, 0u}; \
    ua = MFMA16(__builtin_bit_cast(bf16x8, az), btf, ua); \
    float h0 = fast_tanh(ua[0]), h1 = fast_tanh(ua[1]); \
    float h2 = fast_tanh(ua[2]), h3 = fast_tanh(ua[3]); \
    u32 g0 = ghvp[(t)*2 + 0], g1 = ghvp[(t)*2 + 1]; \
    dv += frombits(g0 & 0xffffu) * (1.f - h0*h0); \
    dv += frombits(g0 >> 16)     * (1.f - h1*h1); \
    dv += frombits(g1 & 0xffffu) * (1.f - h2*h2); \
    dv += frombits(g1 >> 16)     * (1.f - h3*h3); \
    bf16x4 hv; hv[0]=(__bf16)h0; hv[1]=(__bf16)h1; hv[2]=(__bf16)h2; hv[3]=(__bf16)h3; \
    *(bf16x4*)(hb + l16 * 264 + jb + (t)*16 + quad * 4) = hv; }

#define STAGE(st, CTI, DTB, A0, A1, A2, A3) { \
    const float ti = t0 + (CTI) * dt; \
    { \
        bf16x4 yv; \
        yv[0] = (__bf16)(zv[0] + dt * (A0)); \
        yv[1] = (__bf16)(zv[1] + dt * (A1)); \
        yv[2] = (__bf16)(zv[2] + dt * (A2)); \
        yv[3] = (__bf16)(zv[3] + dt * (A3)); \
        *(bf16x4*)(yb + l16 * 72 + colb + quad * 4) = yv; \
    } \
    __syncthreads(); \
    bf16x8 a10 = *(const bf16x8*)(yb + l16 * 72 + quad * 8); \
    bf16x8 a11 = *(const bf16x8*)(yb + l16 * 72 + 32 + quad * 8); \
    bf16x8 btf = {}; \
    if (quad == 0) { btf[0] = (__bf16)ti; btf[1] = (__bf16)1.0f; } \
    float dv = 0.f; \
    MM1T(0) MM1T(1) MM1T(2) MM1T(3) \
    dv += __shfl_xor(dv, 16); \
    dv += __shfl_xor(dv, 32); \
    lp -= (DTB) * dv; \
    __threadfence_block(); /* order own h writes before own h reads (wave-local) */ \
    bf16x8 hc0 = *(const bf16x8*)(hb + l16 * 264 + jb + quad * 8); \
    bf16x8 hc1 = *(const bf16x8*)(hb + l16 * 264 + jb + 32 + quad * 8); \
    f32x4 fa0 = {0.f,0.f,0.f,0.f}, fa1 = fa0, fa2 = fa0, fa3 = fa0; \
    fa0 = MFMA16(w2f[0], hc0, fa0); fa0 = MFMA16(w2f[1], hc1, fa0); \
    fa1 = MFMA16(w2f[2], hc0, fa1); fa1 = MFMA16(w2f[3], hc1, fa1); \
    fa2 = MFMA16(w2f[4], hc0, fa2); fa2 = MFMA16(w2f[5], hc1, fa2); \
    fa3 = MFMA16(w2f[6], hc0, fa3); fa3 = MFMA16(w2f[7], hc1, fa3); \
    { \
        u32x2 p; \
        p[0] = pack2(fa0[0], fa0[1]); p[1] = pack2(fa0[2], fa0[3]); \
        *(u32x2*)(fw + l16 * 68 +  0 + quad * 4) = p; \
        p[0] = pack2(fa1[0], fa1[1]); p[1] = pack2(fa1[2], fa1[3]); \
        *(u32x2*)(fw + l16 * 68 + 16 + quad * 4) = p; \
        p[0] = pack2(fa2[0], fa2[1]); p[1] = pack2(fa2[2], fa2[3]); \
        *(u32x2*)(fw + l16 * 68 + 32 + quad * 4) = p; \
        p[0] = pack2(fa3[0], fa3[1]); p[1] = pack2(fa3[2], fa3[3]); \
        *(u32x2*)(fw + l16 * 68 + 48 + quad * 4) = p; \
    } \
    __syncthreads(); \
    float k0 = bb2[0], k1 = bb2[1], k2 = bb2[2], k3 = bb2[3]; \
    _Pragma("unroll") \
    for (int w = 0; w < 4; ++w) { \
        u32x2 p = *(const u32x2*)(&sFA[grp][w][0] + l16 * 68 + colb + quad * 4); \
        k0 += frombits(p[0] & 0xffffu); k1 += frombits(p[0] >> 16); \
        k2 += frombits(p[1] & 0xffffu); k3 += frombits(p[1] >> 16); \
    } \
    kp[st][0] = pack2(k0, k1); \
    kp[st][1] = pack2(k2, k3); }

    for (int step = 0; step < 8; ++step) {
        const float t0 = dt * (float)step;
        STAGE(0, 0.f,     dt*(35.f/384.f),    0.f,    0.f,    0.f,    0.f)
        STAGE(1, 0.2f,    0.f,                S1A(0), S1A(1), S1A(2), S1A(3))
        STAGE(2, 0.3f,    dt*(500.f/1113.f),  S2A(0), S2A(1), S2A(2), S2A(3))
        STAGE(3, 0.8f,    dt*(125.f/192.f),   S3A(0), S3A(1), S3A(2), S3A(3))
        STAGE(4, 8.f/9.f, dt*(-2187.f/6784.f),S4A(0), S4A(1), S4A(2), S4A(3))
        STAGE(5, 1.f,     dt*(11.f/84.f),     S5A(0), S5A(1), S5A(2), S5A(3))
        zv[0] += dt * CBA(0);
        zv[1] += dt * CBA(1);
        zv[2] += dt * CBA(2);
        zv[3] += dt * CBA(3);
    }

    // ---------------- epilogue ----------------
    *(f32x4*)(Og + row * 64 + colb + quad * 4) = zv;
    float ss = zv[0]*zv[0] + zv[1]*zv[1] + zv[2]*zv[2] + zv[3]*zv[3];
    ss += __shfl_xor(ss, 16);
    ss += __shfl_xor(ss, 32);
    if (quad == 0) {
        sRedSS[wave * 16 + l16] = ss;
        sRedLP[wave * 16 + l16] = lp;
    }
    __syncthreads();
    if (Q == 0 && quad == 0) {
        const float CLOG = -58.8120661f;  // -32*ln(2*pi)
        float sfull = sRedSS[(grp*4 + 0)*16 + l16] + sRedSS[(grp*4 + 1)*16 + l16]
                    + sRedSS[(grp*4 + 2)*16 + l16] + sRedSS[(grp*4 + 3)*16 + l16];
        float lfull = sRedLP[(grp*4 + 0)*16 + l16] + sRedLP[(grp*4 + 1)*16 + l16]
                    + sRedLP[(grp*4 + 2)*16 + l16] + sRedLP[(grp*4 + 3)*16 + l16];
        Og[32768 * 64 + row] = CLOG - 0.5f * sfull - lfull;
    }
}

extern "C" void kernel_launch(void* const* d_in, const int* in_sizes, int n_in,
                              void* d_out, int out_size, void* d_ws, size_t ws_size,
                              hipStream_t stream) {
    const float* Yg  = (const float*)d_in[0];
    const float* Eg  = (const float*)d_in[1];
    const float* W1g = (const float*)d_in[2];  // [65][256]
    const float* b1g = (const float*)d_in[3];
    const float* W2g = (const float*)d_in[4];  // [256][64]
    const float* b2g = (const float*)d_in[5];
    float* Og = (float*)d_out;                 // z (32768*64) then log_px (32768)
    cnf_kernel<<<dim3(1024), dim3(512), 0, stream>>>(Yg, Eg, W1g, b1g, W2g, b2g, Og);
}

// Round 9
// 327.415 us; speedup vs baseline: 3.2438x; 3.2438x over previous
//
#include <hip/hip_runtime.h>

// CNF forward: 8 fixed dopri5 steps x 6 stages, rows independent.
// R9 = R7 VERBATIM except amdgpu_waves_per_eu(4,4) (was (4) min-only).
// R7/R8 evidence: min-only lets the allocator target 8 waves/EU = 64 VGPRs;
// R7's ~100-reg demand spilled ~32 loop-invariant regs (WRITE_SIZE 84MB vs
// 8.5MB real; reloaded every stage from L3), R8's higher demand thrashed L3
// (3.9GB, 1012us). Pinning min=max=4 -> exactly 128-VGPR budget (R2/R3
// showed the allocator respects a two-sided pin), demand fits, no spills.
// Layout per 4-wave group (16 rows): wave Q owns j in [Q*64,+64) and
// output cols [Q*16,+16). 1024 blocks x 512 threads (2 groups/block).

typedef __bf16 bf16x8 __attribute__((ext_vector_type(8)));
typedef __bf16 bf16x4 __attribute__((ext_vector_type(4)));
typedef float  f32x4  __attribute__((ext_vector_type(4)));
typedef unsigned int u32;

#define MFMA16(a, b, c) __builtin_amdgcn_mfma_f32_16x16x32_bf16((a), (b), (c), 0, 0, 0)

__device__ __forceinline__ u32 bfbits(float x) {
    __bf16 b = (__bf16)x;                      // RNE fp32->bf16
    return (u32)__builtin_bit_cast(unsigned short, b);
}
__device__ __forceinline__ float frombits(u32 u16) {
    return __builtin_bit_cast(float, u16 << 16);
}
__device__ __forceinline__ u32 pack2(float lo, float hi) {
    return bfbits(lo) | (bfbits(hi) << 16);
}
__device__ __forceinline__ float fast_tanh(float x) {
    float e = __expf(2.0f * x);
    return 1.0f - 2.0f * __builtin_amdgcn_rcpf(e + 1.0f);
}

extern "C" __global__ __attribute__((amdgpu_waves_per_eu(4, 4))) void
__launch_bounds__(512)
cnf_kernel(const float* __restrict__ Yg, const float* __restrict__ Eg,
           const float* __restrict__ W1g, const float* __restrict__ b1g,
           const float* __restrict__ W2g, const float* __restrict__ b2g,
           float* __restrict__ Og)
{
    // ---- LDS (~27 KB) ----
    __shared__ __align__(16) __bf16 sY[2][16 * 72];    // per-GROUP y buf [batch][d]
    __shared__ __align__(16) __bf16 sH[2][16 * 264];   // per-GROUP h buf [batch][j]
    __shared__ float sB1f[256], sW1tf[256], sBW[256];
    __shared__ float sRedSS[128], sRedLP[128];

    const int tid  = threadIdx.x;
    const int wave = tid >> 6;
    const int lane = tid & 63;
    const int quad = lane >> 4;
    const int l16  = lane & 15;
    const int grp  = wave >> 2;       // 2 groups of 4 waves
    const int Q    = wave & 3;        // wave's slot within group
    const int colb = Q * 16;          // own output-col tile base
    const int jb   = Q * 64;          // own hidden-j base (4 tiles of 16)
    const int row  = blockIdx.x * 32 + grp * 16 + l16;  // this lane's batch row

    // ---------------- bias staging ----------------
    for (int j = tid; j < 256; j += 512) { sB1f[j] = b1g[j]; sW1tf[j] = W1g[64 * 256 + j]; }

    // ---------------- W1 fragments direct from global (A-op: [m=j][k=d]) ----------------
    bf16x8 w1f[8];   // [tile*2 + half]
#define LDW1(t, h) { \
    bf16x8 f; \
    _Pragma("unroll") \
    for (int i = 0; i < 8; ++i) \
        f[i] = (__bf16)W1g[((h)*32 + quad*8 + i) * 256 + jb + (t)*16 + l16]; \
    w1f[(t)*2 + (h)] = f; }
    LDW1(0,0) LDW1(0,1) LDW1(1,0) LDW1(1,1) LDW1(2,0) LDW1(2,1) LDW1(3,0) LDW1(3,1)

    // ---------------- W2^T fragments direct from global (A-op: [m=dout][k=j]) ----------------
    bf16x8 w2f[8];   // [chunk]
#define LDW2(c) { \
    bf16x8 f; \
    _Pragma("unroll") \
    for (int i = 0; i < 8; ++i) \
        f[i] = (__bf16)W2g[((c)*32 + quad*8 + i) * 64 + colb + l16]; \
    w2f[c] = f; }
    LDW2(0) LDW2(1) LDW2(2) LDW2(3) LDW2(4) LDW2(5) LDW2(6) LDW2(7)

    // ---------------- e fragments direct from global ----------------
    // ae: lane (l16=batch, quad) holds e[row][d = quad*8 + i] (+32 for ae1)
    bf16x8 ae0, ae1;
    {
        f32x4 ea = *(const f32x4*)(Eg + row * 64 + quad * 8);
        f32x4 eb = *(const f32x4*)(Eg + row * 64 + quad * 8 + 4);
        f32x4 ec = *(const f32x4*)(Eg + row * 64 + 32 + quad * 8);
        f32x4 ed = *(const f32x4*)(Eg + row * 64 + 32 + quad * 8 + 4);
        ae0[0]=(__bf16)ea[0]; ae0[1]=(__bf16)ea[1]; ae0[2]=(__bf16)ea[2]; ae0[3]=(__bf16)ea[3];
        ae0[4]=(__bf16)eb[0]; ae0[5]=(__bf16)eb[1]; ae0[6]=(__bf16)eb[2]; ae0[7]=(__bf16)eb[3];
        ae1[0]=(__bf16)ec[0]; ae1[1]=(__bf16)ec[1]; ae1[2]=(__bf16)ec[2]; ae1[3]=(__bf16)ec[3];
        ae1[4]=(__bf16)ed[0]; ae1[5]=(__bf16)ed[1]; ae1[6]=(__bf16)ed[2]; ae1[7]=(__bf16)ed[3];
    }

    // ------------- precompute ghv[j][batch] = gh0 .* v, both [j=quad*4+rg][batch=l16] -------
    u32 ghvp[8];   // [tile*2 + pair]
#define PRE(t) { \
    /* v^T = W1a^T @ e^T: A=w1f [m=j][k=d], B=ae [k=d][n=batch] -> C[j][batch] */ \
    f32x4 vacc = {0.f, 0.f, 0.f, 0.f}; \
    vacc = MFMA16(w1f[(t)*2 + 0], ae0, vacc); \
    vacc = MFMA16(w1f[(t)*2 + 1], ae1, vacc); \
    /* gh0^T = W2 @ e^T: A=W2 row j (contiguous d), B=ae -> C[j][batch] */ \
    const float* wrow = W2g + (jb + (t)*16 + l16) * 64; \
    f32x4 wa = *(const f32x4*)(wrow + quad * 8); \
    f32x4 wb = *(const f32x4*)(wrow + quad * 8 + 4); \
    f32x4 wc = *(const f32x4*)(wrow + 32 + quad * 8); \
    f32x4 wd = *(const f32x4*)(wrow + 32 + quad * 8 + 4); \
    bf16x8 aw0, aw1; \
    aw0[0]=(__bf16)wa[0]; aw0[1]=(__bf16)wa[1]; aw0[2]=(__bf16)wa[2]; aw0[3]=(__bf16)wa[3]; \
    aw0[4]=(__bf16)wb[0]; aw0[5]=(__bf16)wb[1]; aw0[6]=(__bf16)wb[2]; aw0[7]=(__bf16)wb[3]; \
    aw1[0]=(__bf16)wc[0]; aw1[1]=(__bf16)wc[1]; aw1[2]=(__bf16)wc[2]; aw1[3]=(__bf16)wc[3]; \
    aw1[4]=(__bf16)wd[0]; aw1[5]=(__bf16)wd[1]; aw1[6]=(__bf16)wd[2]; aw1[7]=(__bf16)wd[3]; \
    f32x4 gacc = {0.f, 0.f, 0.f, 0.f}; \
    gacc = MFMA16(aw0, ae0, gacc); \
    gacc = MFMA16(aw1, ae1, gacc); \
    ghvp[(t)*2 + 0] = pack2(gacc[0] * vacc[0], gacc[1] * vacc[1]); \
    ghvp[(t)*2 + 1] = pack2(gacc[2] * vacc[2], gacc[3] * vacc[3]); }
    PRE(0) PRE(1) PRE(2) PRE(3)

    // ---------------- z state + b2 (lane layout: batch=l16, d=colb+quad*4+rg) -------------
    f32x4 zv  = *(const f32x4*)(Yg + row * 64 + colb + quad * 4);
    f32x4 bb2 = *(const f32x4*)(b2g + colb + quad * 4);

    __bf16* yb = sY[grp];
    __bf16* hb = sH[grp];

    __syncthreads();   // sB1f/sW1tf visible before first STAGE

    const float dt = 0.125f;
    u32 kp[6][2];     // k_dz bf16x2: [stage][pair], d = colb + quad*4 + {0..3}
    float lp = 0.f;   // own-j partial of dlogp (batch = l16)

#define KV(s, g) frombits(((g) & 1) ? (kp[s][(g)>>1] >> 16) : (kp[s][(g)>>1] & 0xffffu))

#define S1A(g) (0.2f*KV(0,g))
#define S2A(g) (0.075f*KV(0,g) + 0.225f*KV(1,g))
#define S3A(g) ((44.f/45.f)*KV(0,g) + (-56.f/15.f)*KV(1,g) + (32.f/9.f)*KV(2,g))
#define S4A(g) ((19372.f/6561.f)*KV(0,g) + (-25360.f/2187.f)*KV(1,g) + \
                (64448.f/6561.f)*KV(2,g) + (-212.f/729.f)*KV(3,g))
#define S5A(g) ((9017.f/3168.f)*KV(0,g) + (-355.f/33.f)*KV(1,g) + \
                (46732.f/5247.f)*KV(2,g) + (49.f/176.f)*KV(3,g) + (-5103.f/18656.f)*KV(4,g))
#define CBA(g) ((35.f/384.f)*KV(0,g) + (500.f/1113.f)*KV(2,g) + (125.f/192.f)*KV(3,g) + \
                (-2187.f/6784.f)*KV(4,g) + (11.f/84.f)*KV(5,g))

    // matmul-1 tile: ua init = bw (bias in accumulator); h packed b64 to hb
#define MM1T(t) { \
    f32x4 ua = *(const f32x4*)(sBW + jb + (t)*16 + quad * 4); \
    ua = MFMA16(w1f[(t)*2 + 0], a10, ua); \
    ua = MFMA16(w1f[(t)*2 + 1], a11, ua); \
    float h0 = fast_tanh(ua[0]), h1 = fast_tanh(ua[1]); \
    float h2 = fast_tanh(ua[2]), h3 = fast_tanh(ua[3]); \
    u32 g0 = ghvp[(t)*2 + 0], g1 = ghvp[(t)*2 + 1]; \
    dv += frombits(g0 & 0xffffu) * (1.f - h0*h0); \
    dv += frombits(g0 >> 16)     * (1.f - h1*h1); \
    dv += frombits(g1 & 0xffffu) * (1.f - h2*h2); \
    dv += frombits(g1 >> 16)     * (1.f - h3*h3); \
    bf16x4 hv; hv[0]=(__bf16)h0; hv[1]=(__bf16)h1; hv[2]=(__bf16)h2; hv[3]=(__bf16)h3; \
    *(bf16x4*)(hb + l16 * 264 + jb + (t)*16 + quad * 4) = hv; }

#define MM2C(c) { \
    bf16x8 hf = *(const bf16x8*)(hb + l16 * 264 + (c)*32 + quad * 8); \
    fa = MFMA16(w2f[c], hf, fa); }

#define STAGE(st, CTI, DTB, A0, A1, A2, A3) { \
    const float ti = t0 + (CTI) * dt; \
    { \
        bf16x4 yv; \
        yv[0] = (__bf16)(zv[0] + dt * (A0)); \
        yv[1] = (__bf16)(zv[1] + dt * (A1)); \
        yv[2] = (__bf16)(zv[2] + dt * (A2)); \
        yv[3] = (__bf16)(zv[3] + dt * (A3)); \
        *(bf16x4*)(yb + l16 * 72 + colb + quad * 4) = yv; \
    } \
    if (tid < 256) sBW[tid] = sB1f[tid] + ti * sW1tf[tid]; \
    __syncthreads(); \
    bf16x8 a10 = *(const bf16x8*)(yb + l16 * 72 + quad * 8); \
    bf16x8 a11 = *(const bf16x8*)(yb + l16 * 72 + 32 + quad * 8); \
    float dv = 0.f; \
    MM1T(0) MM1T(1) MM1T(2) MM1T(3) \
    __syncthreads(); \
    f32x4 fa = bb2; \
    MM2C(0) MM2C(1) MM2C(2) MM2C(3) MM2C(4) MM2C(5) MM2C(6) MM2C(7) \
    kp[st][0] = pack2(fa[0], fa[1]); \
    kp[st][1] = pack2(fa[2], fa[3]); \
    dv += __shfl_xor(dv, 16); \
    dv += __shfl_xor(dv, 32); \
    lp -= (DTB) * dv; }

    for (int step = 0; step < 8; ++step) {
        const float t0 = dt * (float)step;
        STAGE(0, 0.f,     dt*(35.f/384.f),    0.f,    0.f,    0.f,    0.f)
        STAGE(1, 0.2f,    0.f,                S1A(0), S1A(1), S1A(2), S1A(3))
        STAGE(2, 0.3f,    dt*(500.f/1113.f),  S2A(0), S2A(1), S2A(2), S2A(3))
        STAGE(3, 0.8f,    dt*(125.f/192.f),   S3A(0), S3A(1), S3A(2), S3A(3))
        STAGE(4, 8.f/9.f, dt*(-2187.f/6784.f),S4A(0), S4A(1), S4A(2), S4A(3))
        STAGE(5, 1.f,     dt*(11.f/84.f),     S5A(0), S5A(1), S5A(2), S5A(3))
        zv[0] += dt * CBA(0);
        zv[1] += dt * CBA(1);
        zv[2] += dt * CBA(2);
        zv[3] += dt * CBA(3);
    }

    // ---------------- epilogue ----------------
    *(f32x4*)(Og + row * 64 + colb + quad * 4) = zv;
    float ss = zv[0]*zv[0] + zv[1]*zv[1] + zv[2]*zv[2] + zv[3]*zv[3];
    ss += __shfl_xor(ss, 16);
    ss += __shfl_xor(ss, 32);
    if (quad == 0) {
        sRedSS[wave * 16 + l16] = ss;
        sRedLP[wave * 16 + l16] = lp;
    }
    __syncthreads();
    if (Q == 0 && quad == 0) {
        const float CLOG = -58.8120661f;  // -32*ln(2*pi)
        float sfull = sRedSS[(grp*4 + 0)*16 + l16] + sRedSS[(grp*4 + 1)*16 + l16]
                    + sRedSS[(grp*4 + 2)*16 + l16] + sRedSS[(grp*4 + 3)*16 + l16];
        float lfull = sRedLP[(grp*4 + 0)*16 + l16] + sRedLP[(grp*4 + 1)*16 + l16]
                    + sRedLP[(grp*4 + 2)*16 + l16] + sRedLP[(grp*4 + 3)*16 + l16];
        Og[32768 * 64 + row] = CLOG - 0.5f * sfull - lfull;
    }
}

extern "C" void kernel_launch(void* const* d_in, const int* in_sizes, int n_in,
                              void* d_out, int out_size, void* d_ws, size_t ws_size,
                              hipStream_t stream) {
    const float* Yg  = (const float*)d_in[0];
    const float* Eg  = (const float*)d_in[1];
    const float* W1g = (const float*)d_in[2];  // [65][256]
    const float* b1g = (const float*)d_in[3];
    const float* W2g = (const float*)d_in[4];  // [256][64]
    const float* b2g = (const float*)d_in[5];
    float* Og = (float*)d_out;                 // z (32768*64) then log_px (32768)
    cnf_kernel<<<dim3(1024), dim3(512), 0, stream>>>(Yg, Eg, W1g, b1g, W2g, b2g, Og);
}

// Round 10
// 327.329 us; speedup vs baseline: 3.2446x; 1.0003x over previous
//
#include <hip/hip_runtime.h>

// CNF forward: 8 fixed dopri5 steps x 6 stages, rows independent.
// R10 = R9 VERBATIM except __attribute__((amdgpu_num_vgpr(128))) added.
// R7/R9 evidence: waves_per_eu(4)/(4,4) both leave the allocator's occupancy
// heuristic targeting 8 waves/EU = 64 VGPRs; the ~100-reg demand (64 regs of
// loop-invariant W1/W2 frags) spills, and every stage reloads them from
// scratch (WRITE_SIZE 102MB vs 9MB real output). amdgpu-num-vgpr sets the
// allocator's budget DIRECTLY (bypasses the heuristic): 128 regs = 4 waves/EU,
// demand fits, no loop spills, occupancy unchanged at 16 waves/CU.
// Layout per 4-wave group (16 rows): wave Q owns j in [Q*64,+64) and
// output cols [Q*16,+16). 1024 blocks x 512 threads (2 groups/block).

typedef __bf16 bf16x8 __attribute__((ext_vector_type(8)));
typedef __bf16 bf16x4 __attribute__((ext_vector_type(4)));
typedef float  f32x4  __attribute__((ext_vector_type(4)));
typedef unsigned int u32;

#define MFMA16(a, b, c) __builtin_amdgcn_mfma_f32_16x16x32_bf16((a), (b), (c), 0, 0, 0)

__device__ __forceinline__ u32 bfbits(float x) {
    __bf16 b = (__bf16)x;                      // RNE fp32->bf16
    return (u32)__builtin_bit_cast(unsigned short, b);
}
__device__ __forceinline__ float frombits(u32 u16) {
    return __builtin_bit_cast(float, u16 << 16);
}
__device__ __forceinline__ u32 pack2(float lo, float hi) {
    return bfbits(lo) | (bfbits(hi) << 16);
}
__device__ __forceinline__ float fast_tanh(float x) {
    float e = __expf(2.0f * x);
    return 1.0f - 2.0f * __builtin_amdgcn_rcpf(e + 1.0f);
}

extern "C" __global__
__attribute__((amdgpu_waves_per_eu(4, 4)))
__attribute__((amdgpu_num_vgpr(128)))
__launch_bounds__(512)
void cnf_kernel(const float* __restrict__ Yg, const float* __restrict__ Eg,
                const float* __restrict__ W1g, const float* __restrict__ b1g,
                const float* __restrict__ W2g, const float* __restrict__ b2g,
                float* __restrict__ Og)
{
    // ---- LDS (~27 KB) ----
    __shared__ __align__(16) __bf16 sY[2][16 * 72];    // per-GROUP y buf [batch][d]
    __shared__ __align__(16) __bf16 sH[2][16 * 264];   // per-GROUP h buf [batch][j]
    __shared__ float sB1f[256], sW1tf[256], sBW[256];
    __shared__ float sRedSS[128], sRedLP[128];

    const int tid  = threadIdx.x;
    const int wave = tid >> 6;
    const int lane = tid & 63;
    const int quad = lane >> 4;
    const int l16  = lane & 15;
    const int grp  = wave >> 2;       // 2 groups of 4 waves
    const int Q    = wave & 3;        // wave's slot within group
    const int colb = Q * 16;          // own output-col tile base
    const int jb   = Q * 64;          // own hidden-j base (4 tiles of 16)
    const int row  = blockIdx.x * 32 + grp * 16 + l16;  // this lane's batch row

    // ---------------- bias staging ----------------
    for (int j = tid; j < 256; j += 512) { sB1f[j] = b1g[j]; sW1tf[j] = W1g[64 * 256 + j]; }

    // ---------------- W1 fragments direct from global (A-op: [m=j][k=d]) ----------------
    bf16x8 w1f[8];   // [tile*2 + half]
#define LDW1(t, h) { \
    bf16x8 f; \
    _Pragma("unroll") \
    for (int i = 0; i < 8; ++i) \
        f[i] = (__bf16)W1g[((h)*32 + quad*8 + i) * 256 + jb + (t)*16 + l16]; \
    w1f[(t)*2 + (h)] = f; }
    LDW1(0,0) LDW1(0,1) LDW1(1,0) LDW1(1,1) LDW1(2,0) LDW1(2,1) LDW1(3,0) LDW1(3,1)

    // ---------------- W2^T fragments direct from global (A-op: [m=dout][k=j]) ----------------
    bf16x8 w2f[8];   // [chunk]
#define LDW2(c) { \
    bf16x8 f; \
    _Pragma("unroll") \
    for (int i = 0; i < 8; ++i) \
        f[i] = (__bf16)W2g[((c)*32 + quad*8 + i) * 64 + colb + l16]; \
    w2f[c] = f; }
    LDW2(0) LDW2(1) LDW2(2) LDW2(3) LDW2(4) LDW2(5) LDW2(6) LDW2(7)

    // ---------------- e fragments direct from global ----------------
    // ae: lane (l16=batch, quad) holds e[row][d = quad*8 + i] (+32 for ae1)
    bf16x8 ae0, ae1;
    {
        f32x4 ea = *(const f32x4*)(Eg + row * 64 + quad * 8);
        f32x4 eb = *(const f32x4*)(Eg + row * 64 + quad * 8 + 4);
        f32x4 ec = *(const f32x4*)(Eg + row * 64 + 32 + quad * 8);
        f32x4 ed = *(const f32x4*)(Eg + row * 64 + 32 + quad * 8 + 4);
        ae0[0]=(__bf16)ea[0]; ae0[1]=(__bf16)ea[1]; ae0[2]=(__bf16)ea[2]; ae0[3]=(__bf16)ea[3];
        ae0[4]=(__bf16)eb[0]; ae0[5]=(__bf16)eb[1]; ae0[6]=(__bf16)eb[2]; ae0[7]=(__bf16)eb[3];
        ae1[0]=(__bf16)ec[0]; ae1[1]=(__bf16)ec[1]; ae1[2]=(__bf16)ec[2]; ae1[3]=(__bf16)ec[3];
        ae1[4]=(__bf16)ed[0]; ae1[5]=(__bf16)ed[1]; ae1[6]=(__bf16)ed[2]; ae1[7]=(__bf16)ed[3];
    }

    // ------------- precompute ghv[j][batch] = gh0 .* v, both [j=quad*4+rg][batch=l16] -------
    u32 ghvp[8];   // [tile*2 + pair]
#define PRE(t) { \
    /* v^T = W1a^T @ e^T: A=w1f [m=j][k=d], B=ae [k=d][n=batch] -> C[j][batch] */ \
    f32x4 vacc = {0.f, 0.f, 0.f, 0.f}; \
    vacc = MFMA16(w1f[(t)*2 + 0], ae0, vacc); \
    vacc = MFMA16(w1f[(t)*2 + 1], ae1, vacc); \
    /* gh0^T = W2 @ e^T: A=W2 row j (contiguous d), B=ae -> C[j][batch] */ \
    const float* wrow = W2g + (jb + (t)*16 + l16) * 64; \
    f32x4 wa = *(const f32x4*)(wrow + quad * 8); \
    f32x4 wb = *(const f32x4*)(wrow + quad * 8 + 4); \
    f32x4 wc = *(const f32x4*)(wrow + 32 + quad * 8); \
    f32x4 wd = *(const f32x4*)(wrow + 32 + quad * 8 + 4); \
    bf16x8 aw0, aw1; \
    aw0[0]=(__bf16)wa[0]; aw0[1]=(__bf16)wa[1]; aw0[2]=(__bf16)wa[2]; aw0[3]=(__bf16)wa[3]; \
    aw0[4]=(__bf16)wb[0]; aw0[5]=(__bf16)wb[1]; aw0[6]=(__bf16)wb[2]; aw0[7]=(__bf16)wb[3]; \
    aw1[0]=(__bf16)wc[0]; aw1[1]=(__bf16)wc[1]; aw1[2]=(__bf16)wc[2]; aw1[3]=(__bf16)wc[3]; \
    aw1[4]=(__bf16)wd[0]; aw1[5]=(__bf16)wd[1]; aw1[6]=(__bf16)wd[2]; aw1[7]=(__bf16)wd[3]; \
    f32x4 gacc = {0.f, 0.f, 0.f, 0.f}; \
    gacc = MFMA16(aw0, ae0, gacc); \
    gacc = MFMA16(aw1, ae1, gacc); \
    ghvp[(t)*2 + 0] = pack2(gacc[0] * vacc[0], gacc[1] * vacc[1]); \
    ghvp[(t)*2 + 1] = pack2(gacc[2] * vacc[2], gacc[3] * vacc[3]); }
    PRE(0) PRE(1) PRE(2) PRE(3)

    // ---------------- z state + b2 (lane layout: batch=l16, d=colb+quad*4+rg) -------------
    f32x4 zv  = *(const f32x4*)(Yg + row * 64 + colb + quad * 4);
    f32x4 bb2 = *(const f32x4*)(b2g + colb + quad * 4);

    __bf16* yb = sY[grp];
    __bf16* hb = sH[grp];

    __syncthreads();   // sB1f/sW1tf visible before first STAGE

    const float dt = 0.125f;
    u32 kp[6][2];     // k_dz bf16x2: [stage][pair], d = colb + quad*4 + {0..3}
    float lp = 0.f;   // own-j partial of dlogp (batch = l16)

#define KV(s, g) frombits(((g) & 1) ? (kp[s][(g)>>1] >> 16) : (kp[s][(g)>>1] & 0xffffu))

#define S1A(g) (0.2f*KV(0,g))
#define S2A(g) (0.075f*KV(0,g) + 0.225f*KV(1,g))
#define S3A(g) ((44.f/45.f)*KV(0,g) + (-56.f/15.f)*KV(1,g) + (32.f/9.f)*KV(2,g))
#define S4A(g) ((19372.f/6561.f)*KV(0,g) + (-25360.f/2187.f)*KV(1,g) + \
                (64448.f/6561.f)*KV(2,g) + (-212.f/729.f)*KV(3,g))
#define S5A(g) ((9017.f/3168.f)*KV(0,g) + (-355.f/33.f)*KV(1,g) + \
                (46732.f/5247.f)*KV(2,g) + (49.f/176.f)*KV(3,g) + (-5103.f/18656.f)*KV(4,g))
#define CBA(g) ((35.f/384.f)*KV(0,g) + (500.f/1113.f)*KV(2,g) + (125.f/192.f)*KV(3,g) + \
                (-2187.f/6784.f)*KV(4,g) + (11.f/84.f)*KV(5,g))

    // matmul-1 tile: ua init = bw (bias in accumulator); h packed b64 to hb
#define MM1T(t) { \
    f32x4 ua = *(const f32x4*)(sBW + jb + (t)*16 + quad * 4); \
    ua = MFMA16(w1f[(t)*2 + 0], a10, ua); \
    ua = MFMA16(w1f[(t)*2 + 1], a11, ua); \
    float h0 = fast_tanh(ua[0]), h1 = fast_tanh(ua[1]); \
    float h2 = fast_tanh(ua[2]), h3 = fast_tanh(ua[3]); \
    u32 g0 = ghvp[(t)*2 + 0], g1 = ghvp[(t)*2 + 1]; \
    dv += frombits(g0 & 0xffffu) * (1.f - h0*h0); \
    dv += frombits(g0 >> 16)     * (1.f - h1*h1); \
    dv += frombits(g1 & 0xffffu) * (1.f - h2*h2); \
    dv += frombits(g1 >> 16)     * (1.f - h3*h3); \
    bf16x4 hv; hv[0]=(__bf16)h0; hv[1]=(__bf16)h1; hv[2]=(__bf16)h2; hv[3]=(__bf16)h3; \
    *(bf16x4*)(hb + l16 * 264 + jb + (t)*16 + quad * 4) = hv; }

#define MM2C(c) { \
    bf16x8 hf = *(const bf16x8*)(hb + l16 * 264 + (c)*32 + quad * 8); \
    fa = MFMA16(w2f[c], hf, fa); }

#define STAGE(st, CTI, DTB, A0, A1, A2, A3) { \
    const float ti = t0 + (CTI) * dt; \
    { \
        bf16x4 yv; \
        yv[0] = (__bf16)(zv[0] + dt * (A0)); \
        yv[1] = (__bf16)(zv[1] + dt * (A1)); \
        yv[2] = (__bf16)(zv[2] + dt * (A2)); \
        yv[3] = (__bf16)(zv[3] + dt * (A3)); \
        *(bf16x4*)(yb + l16 * 72 + colb + quad * 4) = yv; \
    } \
    if (tid < 256) sBW[tid] = sB1f[tid] + ti * sW1tf[tid]; \
    __syncthreads(); \
    bf16x8 a10 = *(const bf16x8*)(yb + l16 * 72 + quad * 8); \
    bf16x8 a11 = *(const bf16x8*)(yb + l16 * 72 + 32 + quad * 8); \
    float dv = 0.f; \
    MM1T(0) MM1T(1) MM1T(2) MM1T(3) \
    __syncthreads(); \
    f32x4 fa = bb2; \
    MM2C(0) MM2C(1) MM2C(2) MM2C(3) MM2C(4) MM2C(5) MM2C(6) MM2C(7) \
    kp[st][0] = pack2(fa[0], fa[1]); \
    kp[st][1] = pack2(fa[2], fa[3]); \
    dv += __shfl_xor(dv, 16); \
    dv += __shfl_xor(dv, 32); \
    lp -= (DTB) * dv; }

    for (int step = 0; step < 8; ++step) {
        const float t0 = dt * (float)step;
        STAGE(0, 0.f,     dt*(35.f/384.f),    0.f,    0.f,    0.f,    0.f)
        STAGE(1, 0.2f,    0.f,                S1A(0), S1A(1), S1A(2), S1A(3))
        STAGE(2, 0.3f,    dt*(500.f/1113.f),  S2A(0), S2A(1), S2A(2), S2A(3))
        STAGE(3, 0.8f,    dt*(125.f/192.f),   S3A(0), S3A(1), S3A(2), S3A(3))
        STAGE(4, 8.f/9.f, dt*(-2187.f/6784.f),S4A(0), S4A(1), S4A(2), S4A(3))
        STAGE(5, 1.f,     dt*(11.f/84.f),     S5A(0), S5A(1), S5A(2), S5A(3))
        zv[0] += dt * CBA(0);
        zv[1] += dt * CBA(1);
        zv[2] += dt * CBA(2);
        zv[3] += dt * CBA(3);
    }

    // ---------------- epilogue ----------------
    *(f32x4*)(Og + row * 64 + colb + quad * 4) = zv;
    float ss = zv[0]*zv[0] + zv[1]*zv[1] + zv[2]*zv[2] + zv[3]*zv[3];
    ss += __shfl_xor(ss, 16);
    ss += __shfl_xor(ss, 32);
    if (quad == 0) {
        sRedSS[wave * 16 + l16] = ss;
        sRedLP[wave * 16 + l16] = lp;
    }
    __syncthreads();
    if (Q == 0 && quad == 0) {
        const float CLOG = -58.8120661f;  // -32*ln(2*pi)
        float sfull = sRedSS[(grp*4 + 0)*16 + l16] + sRedSS[(grp*4 + 1)*16 + l16]
                    + sRedSS[(grp*4 + 2)*16 + l16] + sRedSS[(grp*4 + 3)*16 + l16];
        float lfull = sRedLP[(grp*4 + 0)*16 + l16] + sRedLP[(grp*4 + 1)*16 + l16]
                    + sRedLP[(grp*4 + 2)*16 + l16] + sRedLP[(grp*4 + 3)*16 + l16];
        Og[32768 * 64 + row] = CLOG - 0.5f * sfull - lfull;
    }
}

extern "C" void kernel_launch(void* const* d_in, const int* in_sizes, int n_in,
                              void* d_out, int out_size, void* d_ws, size_t ws_size,
                              hipStream_t stream) {
    const float* Yg  = (const float*)d_in[0];
    const float* Eg  = (const float*)d_in[1];
    const float* W1g = (const float*)d_in[2];  // [65][256]
    const float* b1g = (const float*)d_in[3];
    const float* W2g = (const float*)d_in[4];  // [256][64]
    const float* b2g = (const float*)d_in[5];
    float* Og = (float*)d_out;                 // z (32768*64) then log_px (32768)
    cnf_kernel<<<dim3(1024), dim3(512), 0, stream>>>(Yg, Eg, W1g, b1g, W2g, b2g, Og);
}